// Round 7
// baseline (442.733 us; speedup 1.0000x reference)
//
#include <hip/hip_runtime.h>
#include <hip/hip_cooperative_groups.h>
#include <math.h>

namespace cg = cooperative_groups;

#define N_HW 12544
#define TN 128               // n per tile
#define NCH 98               // 98 * 128 = 12544
#define NB 64                // batches
#define KBF 8                // fused: blocks per batch
#define NG4 392              // float4 positions per (b,kb) in fused phase 3: 12544/4/8
#define KBB 16               // fallback: blocks per batch

// fused ws layout (floats)
#define FP2 (NB * KBF * 1024)
#define FQP (2 * NB * KBF * 1024)
#define FU  (FQP + NB * KBF * 96)
// fallback ws layout (floats)
#define BP2 (NB * KBB * 1024)
#define BQP (2 * NB * KBB * 1024)
#define BU  (BQP + NB * KBB * 96)

typedef __attribute__((ext_vector_type(8)))  short short8;
typedef __attribute__((ext_vector_type(16))) float f32x16;
typedef __attribute__((ext_vector_type(4)))  float f32x4;

#define MFMA(a, b, c) __builtin_amdgcn_mfma_f32_32x32x16_bf16((a), (b), (c), 0, 0, 0)

// Barrier WITHOUT vmcnt drain: LDS visibility only. Prefetch global loads stay in flight.
#define LDS_BAR()                                                \
    do {                                                         \
        asm volatile("s_waitcnt lgkmcnt(0)" ::: "memory");       \
        __builtin_amdgcn_s_barrier();                            \
        asm volatile("" ::: "memory");                           \
    } while (0)

// 2-way split, 16 mantissa bits captured: f ~= H + M, M rounded-to-nearest (unbiased).
__device__ __forceinline__ void split2(float f, ushort& h, ushort& m) {
    unsigned u = __builtin_bit_cast(unsigned, f);
    h = (ushort)(u >> 16);
    float fh = __builtin_bit_cast(float, u & 0xffff0000u);
    float rm = f - fh;                                   // exact remainder
    unsigned um = __builtin_bit_cast(unsigned, rm);
    um += 0x7fffu + ((um >> 16) & 1u);                   // RNE to bf16
    m = (ushort)(um >> 16);
}

// XOR-swizzled octet slot in a 32-row x 16-octet bf16 tile.
__device__ __forceinline__ int xq(int c, int o) {
    return c * 16 + ((o & 8) | ((o ^ c) & 7));
}

// device-scope coherent scalar load/store (cross-XCD safe: executes at coherent point)
__device__ __forceinline__ float agent_ld(const float* p) {
    return __hip_atomic_load((float*)p, __ATOMIC_RELAXED, __HIP_MEMORY_SCOPE_AGENT);
}
__device__ __forceinline__ void agent_st(float* p, float v) {
    __hip_atomic_store(p, v, __ATOMIC_RELAXED, __HIP_MEMORY_SCOPE_AGENT);
}

// ---- shared phase-1 building-block macros (expand in both kernels' scopes) ----
#define LOADX(PX, jj)                                                          \
    do {                                                                       \
        const float4* xr = (const float4*)(xrow + (size_t)(jj) * TN);          \
        PX[0] = xr[2 * oc];      PX[1] = xr[2 * oc + 1];                       \
        PX[2] = xr[2 * oc + 16]; PX[3] = xr[2 * oc + 17];                      \
    } while (0)

#define LOADP(PP, jj)                                                          \
    do { if (tid < TN) {                                                       \
        const float* pb = pbat + (size_t)((jj) * TN + tid) * 3;                \
        PP[0] = pb[0]; PP[1] = pb[1]; PP[2] = pb[2];                           \
    } } while (0)

#define STAGE(PX, PP)                                                          \
    do {                                                                       \
        _Pragma("unroll")                                                      \
        for (int t = 0; t < 2; ++t) {                                          \
            const int o = oc + 8 * t;                                          \
            float4 f0 = PX[2 * t], f1 = PX[2 * t + 1];                         \
            float fv[8] = {f0.x, f0.y, f0.z, f0.w, f1.x, f1.y, f1.z, f1.w};    \
            unsigned hw[4], mw[4];                                             \
            _Pragma("unroll")                                                  \
            for (int i = 0; i < 4; ++i) {                                      \
                ushort h0, m0, h1, m1;                                         \
                split2(fv[2 * i],     h0, m0);                                 \
                split2(fv[2 * i + 1], h1, m1);                                 \
                hw[i] = (unsigned)h0 | ((unsigned)h1 << 16);                   \
                mw[i] = (unsigned)m0 | ((unsigned)m1 << 16);                   \
            }                                                                  \
            const int s = xq(c, o);                                            \
            XS[s]       = make_uint4(hw[0], hw[1], hw[2], hw[3]);              \
            XS[512 + s] = make_uint4(mw[0], mw[1], mw[2], mw[3]);              \
        }                                                                      \
        if (tid < TN) {                                                        \
            _Pragma("unroll")                                                  \
            for (int r = 0; r < 3; ++r) {                                      \
                ushort h, m;                                                   \
                split2(PP[r], h, m);                                           \
                PTH[r * TN + tid] = h; PTM[r * TN + tid] = m;                  \
            }                                                                  \
        }                                                                      \
    } while (0)

#define MFMA_PHASE()                                                           \
    do {                                                                       \
        __builtin_amdgcn_s_setprio(1);                                         \
        for (int s = wave; s < 8; s += 4) {                                    \
            const int sl = xq(cl, 2 * s + g);                                  \
            short8 xh = __builtin_bit_cast(short8, XS[sl]);                    \
            short8 xm = __builtin_bit_cast(short8, XS[512 + sl]);              \
            const int po = rr * TN + 16 * s + 8 * g;                           \
            short8 ph = *(const short8*)&PTH[po];                              \
            short8 pm = *(const short8*)&PTM[po];                              \
            D1 = MFMA(xh, xh, D1);                                             \
            D1 = MFMA(xm, xm, D1);                                             \
            D2 = MFMA(xh, xm, D2);                                             \
            DQ = MFMA(xh, ph, DQ);                                             \
            DQ = MFMA(xm, ph, DQ);                                             \
            DQ = MFMA(xh, pm, DQ);                                             \
            DQ = MFMA(xm, pm, DQ);                                             \
        }                                                                      \
        __builtin_amdgcn_s_setprio(0);                                         \
    } while (0)

// C/D layout 32x32: col = lane&31, row = (reg&3) + 8*(reg>>2) + 4*(lane>>5)
#define DUMP_REDUCE_G(D, gdst)                                                         \
    __syncthreads();                                                                   \
    _Pragma("unroll")                                                                  \
    for (int i = 0; i < 4; ++i)                                                        \
        *(float4*)&dmp[tid * 20 + 4 * i] =                                             \
            make_float4((D)[4*i], (D)[4*i+1], (D)[4*i+2], (D)[4*i+3]);                 \
    __syncthreads();                                                                   \
    _Pragma("unroll")                                                                  \
    for (int it = 0; it < 4; ++it) {                                                   \
        const int e = tid + 256 * it;                                                  \
        const int r = e >> 5, co = e & 31;                                             \
        const int ln = co + 32 * ((r >> 2) & 1);                                       \
        const int rg = (r & 3) + 4 * (r >> 3);                                         \
        (gdst)[e] = dmp[ln * 20 + rg] + dmp[(64 + ln) * 20 + rg]                       \
                  + dmp[(128 + ln) * 20 + rg] + dmp[(192 + ln) * 20 + rg];             \
    }

#define DUMP_Q(Qdst)                                                                   \
    __syncthreads();                                                                   \
    _Pragma("unroll")                                                                  \
    for (int i = 0; i < 4; ++i)                                                        \
        *(float4*)&dmp[tid * 20 + 4 * i] = make_float4(DQ[4*i], DQ[4*i+1], DQ[4*i+2], DQ[4*i+3]); \
    __syncthreads();                                                                   \
    if (tid < 96) {                                                                    \
        const int c2 = tid / 3, r2 = tid - 3 * c2;                                     \
        const int ln = r2 + 32 * ((c2 >> 2) & 1);                                      \
        const int rg = (c2 & 3) + 4 * (c2 >> 3);                                       \
        float s = dmp[ln * 20 + rg] + dmp[(64 + ln) * 20 + rg]                         \
                + dmp[(128 + ln) * 20 + rg] + dmp[(192 + ln) * 20 + rg];               \
        (Qdst)[tid] = s;                                                               \
    }

// ================= fused cooperative kernel ==========================================
__global__ __launch_bounds__(256, 2)
void k_fused(const float* __restrict__ x, const float* __restrict__ p,
             float* __restrict__ P1, float* __restrict__ P2, float* __restrict__ Qp,
             float* __restrict__ U, float* __restrict__ out)
{
    const int bid = blockIdx.x;
    const int b = bid >> 3, kb = bid & 7;
    const int tid = threadIdx.x;
    const int lane = tid & 63, wave = tid >> 6;

    __shared__ alignas(16) float SMEM[5120];              // XS staging (16 KB) / scratch (20 KB)
    uint4* XS  = (uint4*)SMEM;
    float* dmp = SMEM;
    __shared__ alignas(16) ushort PTH[3 * TN], PTM[3 * TN];
    __shared__ float Us[32][4];

    // ---------------- phase 1: Gram partials (round-5 verified math, stride KBF) ----
    {
        const int c = tid >> 3, oc = tid & 7;
        const float* xrow = x + ((size_t)b * 32 + c) * N_HW;
        const float* pbat = p + (size_t)b * N_HW * 3;

        f32x16 D1 = {0,0,0,0,0,0,0,0,0,0,0,0,0,0,0,0};
        f32x16 D2 = {0,0,0,0,0,0,0,0,0,0,0,0,0,0,0,0};
        f32x16 DQ = {0,0,0,0,0,0,0,0,0,0,0,0,0,0,0,0};
        const int cl = lane & 31, g = lane >> 5;
        const int rr = (cl < 3) ? cl : 0;

        float4 XA[4], XB[4];
        float  PA[3], PB[3];
        int j = kb, jB = kb + KBF;
        LOADX(XA, j); LOADP(PA, j);
        bool hasB = (jB < NCH);
        if (hasB) { LOADX(XB, jB); LOADP(PB, jB); }

        while (true) {
            STAGE(XA, PA);
            const int jn = j + 2 * KBF;
            const bool preA = (jn < NCH);
            if (preA) { LOADX(XA, jn); LOADP(PA, jn); }
            LDS_BAR();
            MFMA_PHASE();
            if (!hasB) break;
            LDS_BAR();

            STAGE(XB, PB);
            const int jn2 = jB + 2 * KBF;
            const bool preB = (jn2 < NCH);
            if (preB) { LOADX(XB, jn2); LOADP(PB, jn2); }
            LDS_BAR();
            MFMA_PHASE();
            if (!preA) break;
            LDS_BAR();

            j = jn; jB = jn2; hasB = preB;
        }

        float* p1 = P1 + ((size_t)b * KBF + kb) * 1024;
        float* p2 = P2 + ((size_t)b * KBF + kb) * 1024;
        DUMP_REDUCE_G(D1, p1)
        DUMP_REDUCE_G(D2, p2)
        DUMP_Q(Qp + ((size_t)b * KBF + kb) * 96)
    }

    __threadfence();                 // flush partial stores out of this XCD's L2
    cg::this_grid().sync();

    // ---------------- phase 2: one solver block per batch (kb==0), coherent reads ---
    if (kb == 0) {
        float* S  = SMEM;            // [1024]
        float* A2 = SMEM + 1024;     // [1024]
        float* Qv = SMEM + 2048;     // [96]
        float* V  = SMEM + 2176;     // [96]
        float* G  = SMEM + 2304;     // [6]
        float* L  = SMEM + 2312;     // [6]

        float a1[4] = {0.f, 0.f, 0.f, 0.f}, a2[4] = {0.f, 0.f, 0.f, 0.f};
        const float* p1 = P1 + (size_t)b * KBF * 1024;
        const float* p2 = P2 + (size_t)b * KBF * 1024;
        #pragma unroll
        for (int kk = 0; kk < KBF; ++kk) {
            #pragma unroll
            for (int i = 0; i < 4; ++i) {
                a1[i] += agent_ld(p1 + kk * 1024 + 4 * tid + i);
                a2[i] += agent_ld(p2 + kk * 1024 + 4 * tid + i);
            }
        }
        #pragma unroll
        for (int i = 0; i < 4; ++i) A2[4 * tid + i] = a2[i];
        if (tid < 96) {
            const float* qp = Qp + (size_t)b * KBF * 96;
            float q = 0.f;
            #pragma unroll
            for (int kk = 0; kk < KBF; ++kk) q += agent_ld(qp + kk * 96 + tid);
            Qv[tid] = q;
        }
        __syncthreads();
        #pragma unroll
        for (int i = 0; i < 4; ++i) {
            const int e = 4 * tid + i;
            const int et = ((e & 31) << 5) | (e >> 5);
            S[e] = a1[i] + a2[i] + A2[et];
        }
        __syncthreads();

        if (tid < 96) {
            const int cc = tid / 3, r = tid % 3;
            float s = 0.f;
            #pragma unroll 8
            for (int c2 = 0; c2 < 32; ++c2) s += S[cc * 32 + c2] * Qv[c2 * 3 + r];
            V[tid] = s;
        }
        for (int round = 0; round < 2; ++round) {
            __syncthreads();
            if (tid < 6) {
                const int r = (tid > 2) ? 2 : ((tid > 0) ? 1 : 0);
                const int s = tid - (r * (r + 1)) / 2;
                float gsum = 0.f;
                for (int c2 = 0; c2 < 32; ++c2) gsum += V[c2 * 3 + r] * V[c2 * 3 + s];
                G[tid] = gsum;
            }
            __syncthreads();
            if (tid == 0) {
                const float l00 = sqrtf(G[0]);
                const float l10 = G[1] / l00, l20 = G[3] / l00;
                const float l11 = sqrtf(G[2] - l10 * l10);
                const float l21 = (G[4] - l20 * l10) / l11;
                const float l22 = sqrtf(G[5] - l20 * l20 - l21 * l21);
                L[0] = l00; L[1] = l10; L[2] = l11; L[3] = l20; L[4] = l21; L[5] = l22;
            }
            __syncthreads();
            if (tid < 32) {
                const float v0 = V[tid * 3 + 0], v1 = V[tid * 3 + 1], v2 = V[tid * 3 + 2];
                const float u0 = v0 / L[0];
                const float u1 = (v1 - L[1] * u0) / L[2];
                const float u2 = (v2 - L[3] * u0 - L[4] * u1) / L[5];
                V[tid * 3 + 0] = u0; V[tid * 3 + 1] = u1; V[tid * 3 + 2] = u2;
            }
        }
        __syncthreads();
        if (tid < 128) {
            const int cc = tid >> 2, r = tid & 3;
            agent_st(U + (size_t)b * 128 + tid, (r < 3) ? V[cc * 3 + r] : 0.f);
        }
    }

    __threadfence();
    cg::this_grid().sync();

    // ---------------- phase 3: out = U * (U^T X) for (b, n-slice kb) ----------------
    if (tid < 128) ((float*)Us)[tid] = agent_ld(U + (size_t)b * 128 + tid);
    __syncthreads();
    {
        const float* Xb = x   + (size_t)b * 32 * N_HW;
        float*       Ob = out + (size_t)b * 32 * N_HW;
        for (int gg = tid; gg < NG4; gg += 256) {
            const size_t off = (size_t)4 * (kb * NG4 + gg);
            float t0x = 0, t0y = 0, t0z = 0, t0w = 0;
            float t1x = 0, t1y = 0, t1z = 0, t1w = 0;
            float t2x = 0, t2y = 0, t2z = 0, t2w = 0;
            #pragma unroll 16
            for (int c = 0; c < 32; ++c) {
                float4 xv = *(const float4*)(Xb + (size_t)c * N_HW + off);
                const float u0 = Us[c][0], u1 = Us[c][1], u2 = Us[c][2];
                t0x += u0 * xv.x; t0y += u0 * xv.y; t0z += u0 * xv.z; t0w += u0 * xv.w;
                t1x += u1 * xv.x; t1y += u1 * xv.y; t1z += u1 * xv.z; t1w += u1 * xv.w;
                t2x += u2 * xv.x; t2y += u2 * xv.y; t2z += u2 * xv.z; t2w += u2 * xv.w;
            }
            #pragma unroll 16
            for (int c = 0; c < 32; ++c) {
                const float u0 = Us[c][0], u1 = Us[c][1], u2 = Us[c][2];
                f32x4 o;
                o.x = u0 * t0x + u1 * t1x + u2 * t2x;
                o.y = u0 * t0y + u1 * t1y + u2 * t2y;
                o.z = u0 * t0z + u1 * t1z + u2 * t2z;
                o.w = u0 * t0w + u1 * t1w + u2 * t2w;
                __builtin_nontemporal_store(o, (f32x4*)(Ob + (size_t)c * N_HW + off));
            }
        }
    }
}

// ================= fallback path: round-5 verified 3-kernel pipeline =================
__global__ __launch_bounds__(256)
void fb_k1(const float* __restrict__ x, const float* __restrict__ p,
           float* __restrict__ P1, float* __restrict__ P2, float* __restrict__ Qp)
{
    const int b = blockIdx.y, kb = blockIdx.x;
    const int tid = threadIdx.x;
    const int lane = tid & 63, wave = tid >> 6;

    __shared__ alignas(16) float SMEM[5120];
    uint4* XS  = (uint4*)SMEM;
    float* dmp = SMEM;
    __shared__ alignas(16) ushort PTH[3 * TN], PTM[3 * TN];

    const int c = tid >> 3, oc = tid & 7;
    const float* xrow = x + ((size_t)b * 32 + c) * N_HW;
    const float* pbat = p + (size_t)b * N_HW * 3;

    f32x16 D1 = {0,0,0,0,0,0,0,0,0,0,0,0,0,0,0,0};
    f32x16 D2 = {0,0,0,0,0,0,0,0,0,0,0,0,0,0,0,0};
    f32x16 DQ = {0,0,0,0,0,0,0,0,0,0,0,0,0,0,0,0};
    const int cl = lane & 31, g = lane >> 5;
    const int rr = (cl < 3) ? cl : 0;

    float4 XA[4], XB[4];
    float  PA[3], PB[3];
    int j = kb, jB = kb + KBB;
    LOADX(XA, j); LOADP(PA, j);
    bool hasB = (jB < NCH);
    if (hasB) { LOADX(XB, jB); LOADP(PB, jB); }

    while (true) {
        STAGE(XA, PA);
        const int jn = j + 2 * KBB;
        const bool preA = (jn < NCH);
        if (preA) { LOADX(XA, jn); LOADP(PA, jn); }
        LDS_BAR();
        MFMA_PHASE();
        if (!hasB) break;
        LDS_BAR();

        STAGE(XB, PB);
        const int jn2 = jB + 2 * KBB;
        const bool preB = (jn2 < NCH);
        if (preB) { LOADX(XB, jn2); LOADP(PB, jn2); }
        LDS_BAR();
        MFMA_PHASE();
        if (!preA) break;
        LDS_BAR();

        j = jn; jB = jn2; hasB = preB;
    }

    float* p1 = P1 + ((size_t)b * KBB + kb) * 1024;
    float* p2 = P2 + ((size_t)b * KBB + kb) * 1024;
    DUMP_REDUCE_G(D1, p1)
    DUMP_REDUCE_G(D2, p2)
    DUMP_Q(Qp + ((size_t)b * KBB + kb) * 96)
}

__global__ __launch_bounds__(256)
void fb_k2(const float* __restrict__ P1, const float* __restrict__ P2,
           const float* __restrict__ Qp, float* __restrict__ Uo)
{
    const int b = blockIdx.x, tid = threadIdx.x;
    __shared__ float S[1024], A2[1024];
    __shared__ float Qv[96], V[96], G[6], L[6];

    f32x4 a1 = {0.f, 0.f, 0.f, 0.f}, a2 = {0.f, 0.f, 0.f, 0.f};
    const float4* p1 = (const float4*)(P1 + (size_t)b * KBB * 1024);
    const float4* p2 = (const float4*)(P2 + (size_t)b * KBB * 1024);
    #pragma unroll 4
    for (int kb = 0; kb < KBB; ++kb) {
        float4 v1 = p1[kb * 256 + tid];
        float4 v2 = p2[kb * 256 + tid];
        a1.x += v1.x; a1.y += v1.y; a1.z += v1.z; a1.w += v1.w;
        a2.x += v2.x; a2.y += v2.y; a2.z += v2.z; a2.w += v2.w;
    }
    A2[4 * tid + 0] = a2.x; A2[4 * tid + 1] = a2.y;
    A2[4 * tid + 2] = a2.z; A2[4 * tid + 3] = a2.w;
    if (tid < 96) {
        const float* qp = Qp + (size_t)b * KBB * 96;
        float q = 0.f;
        #pragma unroll 4
        for (int kb = 0; kb < KBB; ++kb) q += qp[kb * 96 + tid];
        Qv[tid] = q;
    }
    __syncthreads();
    #pragma unroll
    for (int i = 0; i < 4; ++i) {
        const int e = 4 * tid + i;
        const int et = ((e & 31) << 5) | (e >> 5);
        S[e] = ((i == 0) ? a1.x : (i == 1) ? a1.y : (i == 2) ? a1.z : a1.w)
             + ((i == 0) ? a2.x : (i == 1) ? a2.y : (i == 2) ? a2.z : a2.w)
             + A2[et];
    }
    __syncthreads();

    if (tid < 96) {
        const int c = tid / 3, r = tid % 3;
        float s = 0.f;
        #pragma unroll 8
        for (int cc = 0; cc < 32; ++cc) s += S[c * 32 + cc] * Qv[cc * 3 + r];
        V[tid] = s;
    }
    for (int round = 0; round < 2; ++round) {
        __syncthreads();
        if (tid < 6) {
            const int r = (tid > 2) ? 2 : ((tid > 0) ? 1 : 0);
            const int s = tid - (r * (r + 1)) / 2;
            float g = 0.f;
            for (int c = 0; c < 32; ++c) g += V[c * 3 + r] * V[c * 3 + s];
            G[tid] = g;
        }
        __syncthreads();
        if (tid == 0) {
            const float l00 = sqrtf(G[0]);
            const float l10 = G[1] / l00, l20 = G[3] / l00;
            const float l11 = sqrtf(G[2] - l10 * l10);
            const float l21 = (G[4] - l20 * l10) / l11;
            const float l22 = sqrtf(G[5] - l20 * l20 - l21 * l21);
            L[0] = l00; L[1] = l10; L[2] = l11; L[3] = l20; L[4] = l21; L[5] = l22;
        }
        __syncthreads();
        if (tid < 32) {
            const float v0 = V[tid * 3 + 0], v1 = V[tid * 3 + 1], v2 = V[tid * 3 + 2];
            const float u0 = v0 / L[0];
            const float u1 = (v1 - L[1] * u0) / L[2];
            const float u2 = (v2 - L[3] * u0 - L[4] * u1) / L[5];
            V[tid * 3 + 0] = u0; V[tid * 3 + 1] = u1; V[tid * 3 + 2] = u2;
        }
    }
    __syncthreads();
    if (tid < 32) {
        Uo[(size_t)b * 128 + tid * 4 + 0] = V[tid * 3 + 0];
        Uo[(size_t)b * 128 + tid * 4 + 1] = V[tid * 3 + 1];
        Uo[(size_t)b * 128 + tid * 4 + 2] = V[tid * 3 + 2];
        Uo[(size_t)b * 128 + tid * 4 + 3] = 0.f;
    }
}

__global__ __launch_bounds__(256)
void fb_k3(const float* __restrict__ x, const float* __restrict__ Uw,
           float* __restrict__ out)
{
    const int b = blockIdx.y, tid = threadIdx.x;
    __shared__ float Us[32][4];
    if (tid < 128) ((float*)Us)[tid] = Uw[(size_t)b * 128 + tid];
    __syncthreads();
    const int g = blockIdx.x * 256 + tid;
    if (g >= N_HW / 4) return;

    const float* Xb = x   + (size_t)b * 32 * N_HW + 4 * (size_t)g;
    float*       Ob = out + (size_t)b * 32 * N_HW + 4 * (size_t)g;

    float t0x = 0, t0y = 0, t0z = 0, t0w = 0;
    float t1x = 0, t1y = 0, t1z = 0, t1w = 0;
    float t2x = 0, t2y = 0, t2z = 0, t2w = 0;
    #pragma unroll 16
    for (int c = 0; c < 32; ++c) {
        float4 xv = *(const float4*)(Xb + (size_t)c * N_HW);
        const float u0 = Us[c][0], u1 = Us[c][1], u2 = Us[c][2];
        t0x += u0 * xv.x; t0y += u0 * xv.y; t0z += u0 * xv.z; t0w += u0 * xv.w;
        t1x += u1 * xv.x; t1y += u1 * xv.y; t1z += u1 * xv.z; t1w += u1 * xv.w;
        t2x += u2 * xv.x; t2y += u2 * xv.y; t2z += u2 * xv.z; t2w += u2 * xv.w;
    }
    #pragma unroll 16
    for (int c = 0; c < 32; ++c) {
        const float u0 = Us[c][0], u1 = Us[c][1], u2 = Us[c][2];
        f32x4 o;
        o.x = u0 * t0x + u1 * t1x + u2 * t2x;
        o.y = u0 * t0y + u1 * t1y + u2 * t2y;
        o.z = u0 * t0z + u1 * t1z + u2 * t2z;
        o.w = u0 * t0w + u1 * t1w + u2 * t2w;
        __builtin_nontemporal_store(o, (f32x4*)(Ob + (size_t)c * N_HW));
    }
}

extern "C" void kernel_launch(void* const* d_in, const int* in_sizes, int n_in,
                              void* d_out, int out_size, void* d_ws, size_t ws_size,
                              hipStream_t stream)
{
    const float* x = (const float*)d_in[0];
    const float* p = (const float*)d_in[1];
    float* ws = (float*)d_ws;
    float* out = (float*)d_out;

    // fused layout
    float* P1 = ws;
    float* P2 = ws + FP2;
    float* Qp = ws + FQP;
    float* U  = ws + FU;

    void* args[] = { (void*)&x, (void*)&p, (void*)&P1, (void*)&P2, (void*)&Qp,
                     (void*)&U, (void*)&out };
    hipError_t err = hipLaunchCooperativeKernel((const void*)k_fused, dim3(NB * KBF),
                                                dim3(256), args, 0, stream);
    if (err != hipSuccess) {
        (void)hipGetLastError();   // clear sticky error state
        // fallback layout (disjoint use; same ws base, exclusive execution)
        float* bP1 = ws;
        float* bP2 = ws + BP2;
        float* bQp = ws + BQP;
        float* bU  = ws + BU;
        hipLaunchKernelGGL(fb_k1, dim3(KBB, NB), dim3(256), 0, stream, x, p, bP1, bP2, bQp);
        hipLaunchKernelGGL(fb_k2, dim3(NB), dim3(256), 0, stream, bP1, bP2, bQp, bU);
        hipLaunchKernelGGL(fb_k3, dim3((N_HW / 4 + 255) / 256, NB), dim3(256), 0, stream, x, bU, out);
    }
}

// Round 8
// 228.048 us; speedup vs baseline: 1.9414x; 1.9414x over previous
//
#include <hip/hip_runtime.h>
#include <math.h>

#define N_HW 12544
#define TN 128               // n per block tile
#define NCH 98               // 98 * 128 = 12544
#define KB 16                // blocks per batch; block kb owns a CONTIGUOUS tile range

// ws layout (floats): P1[64][KB][1024], P2[64][KB][1024], Qp[64][KB][96], U[64][128]
#define WS_P1 0
#define WS_P2 (64 * KB * 1024)
#define WS_QP (2 * 64 * KB * 1024)
#define WS_U  (WS_QP + 64 * KB * 96)

typedef __attribute__((ext_vector_type(8)))  short short8;
typedef __attribute__((ext_vector_type(16))) float f32x16;
typedef __attribute__((ext_vector_type(4)))  float f32x4;

#define MFMA(a, b, c) __builtin_amdgcn_mfma_f32_32x32x16_bf16((a), (b), (c), 0, 0, 0)

// Barrier WITHOUT vmcnt drain: LDS visibility only. Prefetch global loads stay in flight.
#define LDS_BAR()                                                \
    do {                                                         \
        asm volatile("s_waitcnt lgkmcnt(0)" ::: "memory");       \
        __builtin_amdgcn_s_barrier();                            \
        asm volatile("" ::: "memory");                           \
    } while (0)

// 2-way split, 16 mantissa bits captured: f ~= H + M, M rounded-to-nearest (unbiased).
__device__ __forceinline__ void split2(float f, ushort& h, ushort& m) {
    unsigned u = __builtin_bit_cast(unsigned, f);
    h = (ushort)(u >> 16);
    float fh = __builtin_bit_cast(float, u & 0xffff0000u);
    float rm = f - fh;                                   // exact remainder
    unsigned um = __builtin_bit_cast(unsigned, rm);
    um += 0x7fffu + ((um >> 16) & 1u);                   // RNE to bf16
    m = (ushort)(um >> 16);
}

// XOR-swizzled octet slot in a 32-row x 16-octet bf16 tile.
__device__ __forceinline__ int xq(int c, int o) {
    return c * 16 + ((o & 8) | ((o ^ c) & 7));
}

// ---------------- k1: persistent MFMA Gram partials (2-plane, DENSE loads) -----------
// Block (b,kb) owns contiguous tiles [j0, j0+T).  X loads are instruction-dense:
// instruction k reads lanes oc=0..7 at consecutive float4s 8k+oc -> 128 B fully-used
// cache lines per row per instruction (was 16B-at-32B-stride: every line half-used
// per instruction => ~770 GB/s delivered; k3's dense pattern gets ~6 TB/s).
__global__ __launch_bounds__(256)
void k1_gram(const float* __restrict__ x, const float* __restrict__ p,
             float* __restrict__ P1, float* __restrict__ P2, float* __restrict__ Qp)
{
    const int b = blockIdx.y, kb = blockIdx.x;
    const int tid = threadIdx.x;
    const int lane = tid & 63, wave = tid >> 6;

    // SMEM union: XS staging (2 planes x 512 uint4 = 16 KB) / reduce scratch (20 KB)
    __shared__ alignas(16) float SMEM[5120];
    uint4* XS  = (uint4*)SMEM;
    float* dmp = SMEM;
    __shared__ alignas(16) ushort PTH[3 * TN], PTM[3 * TN];   // P^T tiles [r][n]

    const int c = tid >> 3, oc = tid & 7;
    const float* xrow = x + ((size_t)b * 32 + c) * N_HW;
    const float* pbat = p + (size_t)b * N_HW * 3;

    f32x16 D1 = {0,0,0,0,0,0,0,0,0,0,0,0,0,0,0,0};
    f32x16 D2 = {0,0,0,0,0,0,0,0,0,0,0,0,0,0,0,0};
    f32x16 DQ = {0,0,0,0,0,0,0,0,0,0,0,0,0,0,0,0};
    const int cl = lane & 31, g = lane >> 5;
    const int rr = (cl < 3) ? cl : 0;

    // contiguous range: 98 = 2*7 + 14*6
    const int T  = (kb < 2) ? 7 : 6;
    const int j0 = kb * 6 + ((kb < 2) ? kb : 2);

#define LOADX(PX, jj)                                                          \
    do {                                                                       \
        const float4* xr = (const float4*)(xrow + (size_t)(jj) * TN);          \
        PX[0] = xr[oc];      PX[1] = xr[8 + oc];                               \
        PX[2] = xr[16 + oc]; PX[3] = xr[24 + oc];                              \
    } while (0)

#define LOADP(PP, jj)                                                          \
    do { if (tid < TN) {                                                       \
        const float* pb = pbat + (size_t)((jj) * TN + tid) * 3;                \
        PP[0] = pb[0]; PP[1] = pb[1]; PP[2] = pb[2];                           \
    } } while (0)

// Thread (c,oc), PX[k] holds n = 32k+4oc .. +3 = octet o=4k+(oc>>1), half h=oc&1.
// Write the SAME swizzled XS layout as before via uint2 half-octets; MFMA reads unchanged.
#define STAGE(PX, PP)                                                          \
    do {                                                                       \
        uint2* XH = (uint2*)XS;                                                \
        uint2* XM = (uint2*)(XS + 512);                                        \
        _Pragma("unroll")                                                      \
        for (int k = 0; k < 4; ++k) {                                          \
            float4 f = PX[k];                                                  \
            ushort h0, m0, h1, m1, h2, m2, h3, m3;                             \
            split2(f.x, h0, m0); split2(f.y, h1, m1);                          \
            split2(f.z, h2, m2); split2(f.w, h3, m3);                          \
            const int o  = 4 * k + (oc >> 1);                                  \
            const int s2 = xq(c, o) * 2 + (oc & 1);                            \
            XH[s2] = make_uint2((unsigned)h0 | ((unsigned)h1 << 16),           \
                                (unsigned)h2 | ((unsigned)h3 << 16));          \
            XM[s2] = make_uint2((unsigned)m0 | ((unsigned)m1 << 16),           \
                                (unsigned)m2 | ((unsigned)m3 << 16));          \
        }                                                                      \
        if (tid < TN) {                                                        \
            _Pragma("unroll")                                                  \
            for (int r = 0; r < 3; ++r) {                                      \
                ushort h, m;                                                   \
                split2(PP[r], h, m);                                           \
                PTH[r * TN + tid] = h; PTM[r * TN + tid] = m;                  \
            }                                                                  \
        }                                                                      \
    } while (0)

#define MFMA_PHASE()                                                           \
    do {                                                                       \
        __builtin_amdgcn_s_setprio(1);                                         \
        for (int s = wave; s < 8; s += 4) {                                    \
            const int sl = xq(cl, 2 * s + g);                                  \
            short8 xh = __builtin_bit_cast(short8, XS[sl]);                    \
            short8 xm = __builtin_bit_cast(short8, XS[512 + sl]);              \
            const int po = rr * TN + 16 * s + 8 * g;                           \
            short8 ph = *(const short8*)&PTH[po];                              \
            short8 pm = *(const short8*)&PTM[po];                              \
            D1 = MFMA(xh, xh, D1);                                             \
            D1 = MFMA(xm, xm, D1);                                             \
            D2 = MFMA(xh, xm, D2);                                             \
            DQ = MFMA(xh, ph, DQ);                                             \
            DQ = MFMA(xm, ph, DQ);                                             \
            DQ = MFMA(xh, pm, DQ);                                             \
            DQ = MFMA(xm, pm, DQ);                                             \
        }                                                                      \
        __builtin_amdgcn_s_setprio(0);                                         \
    } while (0)

    // ---- fixed-trip statically-unrolled pipeline, depth-2 clamped prefetch ----
    float4 XA[4], XB[4];
    float  PA[3], PB[3];
    LOADX(XA, j0);     LOADP(PA, j0);
    LOADX(XB, j0 + 1); LOADP(PB, j0 + 1);

#define STEP(PX, PP, t)                                                        \
    if ((t) < T) {                                                             \
        STAGE(PX, PP);                                                         \
        const int jp = j0 + (((t) + 2 < T) ? (t) + 2 : T - 1);                 \
        LOADX(PX, jp); LOADP(PP, jp);                                          \
        LDS_BAR();                                                             \
        MFMA_PHASE();                                                          \
        if ((t) + 1 < T) LDS_BAR();                                            \
    }

    STEP(XA, PA, 0)
    STEP(XB, PB, 1)
    STEP(XA, PA, 2)
    STEP(XB, PB, 3)
    STEP(XA, PA, 4)
    STEP(XB, PB, 5)
    STEP(XA, PA, 6)

    // ---- cross-wave reduce (stride-20 LDS scratch, conflict-free b128 writes) ----
    // C/D layout 32x32: col = lane&31, row = (reg&3) + 8*(reg>>2) + 4*(lane>>5)
    #define DUMP_REDUCE_G(D, gdst)                                                         \
        __syncthreads();                                                                   \
        _Pragma("unroll")                                                                  \
        for (int i = 0; i < 4; ++i)                                                        \
            *(float4*)&dmp[tid * 20 + 4 * i] =                                             \
                make_float4((D)[4*i], (D)[4*i+1], (D)[4*i+2], (D)[4*i+3]);                 \
        __syncthreads();                                                                   \
        _Pragma("unroll")                                                                  \
        for (int it = 0; it < 4; ++it) {                                                   \
            const int e = tid + 256 * it;                                                  \
            const int r = e >> 5, co = e & 31;                                             \
            const int ln = co + 32 * ((r >> 2) & 1);                                       \
            const int rg = (r & 3) + 4 * (r >> 3);                                         \
            (gdst)[e] = dmp[ln * 20 + rg] + dmp[(64 + ln) * 20 + rg]                       \
                      + dmp[(128 + ln) * 20 + rg] + dmp[(192 + ln) * 20 + rg];             \
        }

    float* p1 = P1 + ((size_t)b * KB + kb) * 1024;
    float* p2 = P2 + ((size_t)b * KB + kb) * 1024;
    DUMP_REDUCE_G(D1, p1)
    DUMP_REDUCE_G(D2, p2)

    // ---- Q partial ----
    __syncthreads();
    #pragma unroll
    for (int i = 0; i < 4; ++i)
        *(float4*)&dmp[tid * 20 + 4 * i] = make_float4(DQ[4*i], DQ[4*i+1], DQ[4*i+2], DQ[4*i+3]);
    __syncthreads();
    if (tid < 96) {
        const int c2 = tid / 3, r2 = tid - 3 * c2;
        const int ln = r2 + 32 * ((c2 >> 2) & 1);
        const int rg = (c2 & 3) + 4 * (c2 >> 3);
        float s = dmp[ln * 20 + rg] + dmp[(64 + ln) * 20 + rg]
                + dmp[(128 + ln) * 20 + rg] + dmp[(192 + ln) * 20 + rg];
        Qp[((size_t)b * KB + kb) * 96 + tid] = s;
    }
}

// ---------------- k2: reduce partials -> S, Q; V = S*Q0; CholQR2 -> U (32x3, padded) --
__global__ __launch_bounds__(256)
void k2_solve(const float* __restrict__ P1, const float* __restrict__ P2,
              const float* __restrict__ Qp, float* __restrict__ Uo)
{
    const int b = blockIdx.x, tid = threadIdx.x;
    __shared__ float S[1024], A2[1024];
    __shared__ float Qv[96], V[96], G[6], L[6];

    f32x4 a1 = {0.f, 0.f, 0.f, 0.f}, a2 = {0.f, 0.f, 0.f, 0.f};
    const float4* p1 = (const float4*)(P1 + (size_t)b * KB * 1024);
    const float4* p2 = (const float4*)(P2 + (size_t)b * KB * 1024);
    #pragma unroll 4
    for (int kb = 0; kb < KB; ++kb) {
        float4 v1 = p1[kb * 256 + tid];
        float4 v2 = p2[kb * 256 + tid];
        a1.x += v1.x; a1.y += v1.y; a1.z += v1.z; a1.w += v1.w;
        a2.x += v2.x; a2.y += v2.y; a2.z += v2.z; a2.w += v2.w;
    }
    A2[4 * tid + 0] = a2.x; A2[4 * tid + 1] = a2.y;
    A2[4 * tid + 2] = a2.z; A2[4 * tid + 3] = a2.w;
    if (tid < 96) {
        const float* qp = Qp + (size_t)b * KB * 96;
        float q = 0.f;
        #pragma unroll 4
        for (int kb = 0; kb < KB; ++kb) q += qp[kb * 96 + tid];
        Qv[tid] = q;
    }
    __syncthreads();
    #pragma unroll
    for (int i = 0; i < 4; ++i) {
        const int e = 4 * tid + i;
        const int et = ((e & 31) << 5) | (e >> 5);
        S[e] = ((i == 0) ? a1.x : (i == 1) ? a1.y : (i == 2) ? a1.z : a1.w)
             + ((i == 0) ? a2.x : (i == 1) ? a2.y : (i == 2) ? a2.z : a2.w)
             + A2[et];
    }
    __syncthreads();

    if (tid < 96) {
        const int c = tid / 3, r = tid % 3;
        float s = 0.f;
        #pragma unroll 8
        for (int cc = 0; cc < 32; ++cc) s += S[c * 32 + cc] * Qv[cc * 3 + r];
        V[tid] = s;
    }
    for (int round = 0; round < 2; ++round) {
        __syncthreads();
        if (tid < 6) {
            const int r = (tid > 2) ? 2 : ((tid > 0) ? 1 : 0);
            const int s = tid - (r * (r + 1)) / 2;
            float g = 0.f;
            for (int c = 0; c < 32; ++c) g += V[c * 3 + r] * V[c * 3 + s];
            G[tid] = g;
        }
        __syncthreads();
        if (tid == 0) {
            const float l00 = sqrtf(G[0]);
            const float l10 = G[1] / l00, l20 = G[3] / l00;
            const float l11 = sqrtf(G[2] - l10 * l10);
            const float l21 = (G[4] - l20 * l10) / l11;
            const float l22 = sqrtf(G[5] - l20 * l20 - l21 * l21);
            L[0] = l00; L[1] = l10; L[2] = l11; L[3] = l20; L[4] = l21; L[5] = l22;
        }
        __syncthreads();
        if (tid < 32) {
            const float v0 = V[tid * 3 + 0], v1 = V[tid * 3 + 1], v2 = V[tid * 3 + 2];
            const float u0 = v0 / L[0];
            const float u1 = (v1 - L[1] * u0) / L[2];
            const float u2 = (v2 - L[3] * u0 - L[4] * u1) / L[5];
            V[tid * 3 + 0] = u0; V[tid * 3 + 1] = u1; V[tid * 3 + 2] = u2;
        }
    }
    __syncthreads();
    if (tid < 32) {
        Uo[(size_t)b * 128 + tid * 4 + 0] = V[tid * 3 + 0];
        Uo[(size_t)b * 128 + tid * 4 + 1] = V[tid * 3 + 1];
        Uo[(size_t)b * 128 + tid * 4 + 2] = V[tid * 3 + 2];
        Uo[(size_t)b * 128 + tid * 4 + 3] = 0.f;
    }
}

// ---------------- k3: out = U * (U^T X), pure streaming ----------------
__global__ __launch_bounds__(256)
void k3_out(const float* __restrict__ x, const float* __restrict__ Uw,
            float* __restrict__ out)
{
    const int b = blockIdx.y, tid = threadIdx.x;
    __shared__ float Us[32][4];
    if (tid < 128) ((float*)Us)[tid] = Uw[(size_t)b * 128 + tid];
    __syncthreads();
    const int g = blockIdx.x * 256 + tid;
    if (g >= N_HW / 4) return;

    const float* Xb = x   + (size_t)b * 32 * N_HW + 4 * (size_t)g;
    float*       Ob = out + (size_t)b * 32 * N_HW + 4 * (size_t)g;

    float t0x = 0, t0y = 0, t0z = 0, t0w = 0;
    float t1x = 0, t1y = 0, t1z = 0, t1w = 0;
    float t2x = 0, t2y = 0, t2z = 0, t2w = 0;
    #pragma unroll 16
    for (int c = 0; c < 32; ++c) {
        float4 xv = *(const float4*)(Xb + (size_t)c * N_HW);
        const float u0 = Us[c][0], u1 = Us[c][1], u2 = Us[c][2];
        t0x += u0 * xv.x; t0y += u0 * xv.y; t0z += u0 * xv.z; t0w += u0 * xv.w;
        t1x += u1 * xv.x; t1y += u1 * xv.y; t1z += u1 * xv.z; t1w += u1 * xv.w;
        t2x += u2 * xv.x; t2y += u2 * xv.y; t2z += u2 * xv.z; t2w += u2 * xv.w;
    }
    #pragma unroll 16
    for (int c = 0; c < 32; ++c) {
        const float u0 = Us[c][0], u1 = Us[c][1], u2 = Us[c][2];
        f32x4 o;
        o.x = u0 * t0x + u1 * t1x + u2 * t2x;
        o.y = u0 * t0y + u1 * t1y + u2 * t2y;
        o.z = u0 * t0z + u1 * t1z + u2 * t2z;
        o.w = u0 * t0w + u1 * t1w + u2 * t2w;
        __builtin_nontemporal_store(o, (f32x4*)(Ob + (size_t)c * N_HW));
    }
}

extern "C" void kernel_launch(void* const* d_in, const int* in_sizes, int n_in,
                              void* d_out, int out_size, void* d_ws, size_t ws_size,
                              hipStream_t stream)
{
    const float* x = (const float*)d_in[0];
    const float* p = (const float*)d_in[1];
    float* ws = (float*)d_ws;
    float* P1 = ws + WS_P1;
    float* P2 = ws + WS_P2;
    float* Qp = ws + WS_QP;
    float* U  = ws + WS_U;
    float* out = (float*)d_out;

    hipLaunchKernelGGL(k1_gram, dim3(KB, 64), dim3(256), 0, stream, x, p, P1, P2, Qp);
    hipLaunchKernelGGL(k2_solve, dim3(64), dim3(256), 0, stream, P1, P2, Qp, U);
    hipLaunchKernelGGL(k3_out, dim3((N_HW / 4 + 255) / 256, 64), dim3(256), 0, stream, x, U, out);
}